// Round 2
// baseline (248.489 us; speedup 1.0000x reference)
//
#include <hip/hip_runtime.h>
#include <hip/hip_bf16.h>

#define D_DIM 128
#define MT 64            // node rows per block (4 waves x 16-row tiles)
#define LDSS 136         // 128 + 8 bf16 pad: +4-bank rotation/row, 16B-aligned rows

typedef __attribute__((ext_vector_type(8))) short bf16x8;
typedef __attribute__((ext_vector_type(4))) float f32x4;

__device__ __forceinline__ unsigned short f2bf(float f) {
    return __builtin_bit_cast(unsigned short, __float2bfloat16(f));
}

__global__ void prep_weights(const float* __restrict__ w1,
                             const float* __restrict__ w2,
                             unsigned short* __restrict__ w1b,
                             unsigned short* __restrict__ w2b) {
    int t = blockIdx.x * blockDim.x + threadIdx.x;
    if (t < D_DIM * D_DIM) {
        w1b[t] = f2bf(w1[t]);
        w2b[t] = f2bf(w2[t]);
    }
}

__global__ __launch_bounds__(256, 8)
void ctx_encoder(const int* __restrict__ nodes,
                 const float* __restrict__ c2e,
                 const unsigned short* __restrict__ w1b,
                 const float* __restrict__ b1,
                 const unsigned short* __restrict__ w2b,
                 const float* __restrict__ b2,
                 float* __restrict__ out,
                 int N) {
    __shared__ unsigned short sH[MT][LDSS];   // h transpose buffer only (17.4 KB)

    const int t    = threadIdx.x;
    const int lane = t & 63;
    const int wave = t >> 6;
    const int m0   = wave * 16;     // wave's 16-row tile
    const int cl   = lane & 15;
    const int quad = lane >> 4;
    const int rb   = quad * 4;      // C/D row base: row = quad*4 + reg

    // ---- gather A-fragments straight from global (fp32), convert in regs ----
    // A-frag layout: lane holds A[m=cl][k = quad*8 + j], j=0..7, per 32-wide k-step
    int gr = blockIdx.x * MT + m0 + cl;
    int grc = gr < N ? gr : N - 1;
    const int idx = nodes[grc];
    const float* rowp = c2e + (size_t)idx * D_DIM + quad * 8;

    float4 g[8];
    #pragma unroll
    for (int ks = 0; ks < 4; ++ks) {
        g[2 * ks]     = *(const float4*)(rowp + ks * 32);
        g[2 * ks + 1] = *(const float4*)(rowp + ks * 32 + 4);
    }
    bf16x8 aF[4];
    #pragma unroll
    for (int ks = 0; ks < 4; ++ks) {
        bf16x8 a;
        a[0] = (short)f2bf(g[2 * ks].x);     a[1] = (short)f2bf(g[2 * ks].y);
        a[2] = (short)f2bf(g[2 * ks].z);     a[3] = (short)f2bf(g[2 * ks].w);
        a[4] = (short)f2bf(g[2 * ks + 1].x); a[5] = (short)f2bf(g[2 * ks + 1].y);
        a[6] = (short)f2bf(g[2 * ks + 1].z); a[7] = (short)f2bf(g[2 * ks + 1].w);
        aF[ks] = a;
    }

    // ---- layer 1: h = relu(ce @ W1^T + b1), h -> LDS (bf16, transposed access next) ----
    #pragma unroll
    for (int ct = 0; ct < 8; ++ct) {
        f32x4 acc = {0.f, 0.f, 0.f, 0.f};
        #pragma unroll
        for (int ks = 0; ks < 4; ++ks) {
            // W row-major [i][k] is exactly the B^T fragment layout
            bf16x8 bF = *(const bf16x8*)&w1b[(ct * 16 + cl) * D_DIM + ks * 32 + quad * 8];
            acc = __builtin_amdgcn_mfma_f32_16x16x32_bf16(aF[ks], bF, acc, 0, 0, 0);
        }
        const int j = ct * 16 + cl;
        const float bias = b1[j];
        #pragma unroll
        for (int r = 0; r < 4; ++r) {
            float h = acc[r] + bias;
            h = h > 0.f ? h : 0.f;
            sH[m0 + rb + r][j] = f2bf(h);
        }
    }
    __syncthreads();

    // ---- layer 2: out = relu(h @ W2^T + b2) ----
    bf16x8 hF[4];
    #pragma unroll
    for (int ks = 0; ks < 4; ++ks)
        hF[ks] = *(const bf16x8*)&sH[m0 + cl][ks * 32 + quad * 8];

    #pragma unroll
    for (int ct = 0; ct < 8; ++ct) {
        f32x4 acc = {0.f, 0.f, 0.f, 0.f};
        #pragma unroll
        for (int ks = 0; ks < 4; ++ks) {
            bf16x8 bF = *(const bf16x8*)&w2b[(ct * 16 + cl) * D_DIM + ks * 32 + quad * 8];
            acc = __builtin_amdgcn_mfma_f32_16x16x32_bf16(hF[ks], bF, acc, 0, 0, 0);
        }
        const int j = ct * 16 + cl;
        const float bias = b2[j];
        #pragma unroll
        for (int r = 0; r < 4; ++r) {
            float o = acc[r] + bias;
            o = o > 0.f ? o : 0.f;
            const int grow = blockIdx.x * MT + m0 + rb + r;
            if (grow < N)
                out[(size_t)grow * D_DIM + j] = o;
        }
    }
}

extern "C" void kernel_launch(void* const* d_in, const int* in_sizes, int n_in,
                              void* d_out, int out_size, void* d_ws, size_t ws_size,
                              hipStream_t stream) {
    const int*   nodes = (const int*)d_in[0];
    const float* c2e   = (const float*)d_in[1];
    const float* w1    = (const float*)d_in[2];
    const float* b1    = (const float*)d_in[3];
    const float* w2    = (const float*)d_in[4];
    const float* b2    = (const float*)d_in[5];
    float* out = (float*)d_out;
    const int N = in_sizes[0];

    unsigned short* w1b = (unsigned short*)d_ws;
    unsigned short* w2b = w1b + D_DIM * D_DIM;

    // ws is re-poisoned before every call -> must reconvert weights each launch
    prep_weights<<<dim3((D_DIM * D_DIM + 255) / 256), dim3(256), 0, stream>>>(w1, w2, w1b, w2b);

    const int grid = (N + MT - 1) / MT;
    ctx_encoder<<<dim3(grid), dim3(256), 0, stream>>>(nodes, c2e, w1b, b1, w2b, b2, out, N);
}

// Round 3
// 178.944 us; speedup vs baseline: 1.3886x; 1.3886x over previous
//
#include <hip/hip_runtime.h>
#include <hip/hip_bf16.h>

#define D_DIM 128
#define MT 128           // node rows per block (4 waves x 2 m-tiles x 16 rows)
#define LDSS 136         // 128 + 8 bf16 pad: +4-bank rotation/row, 16B-aligned rows

typedef __attribute__((ext_vector_type(8))) short bf16x8;
typedef __attribute__((ext_vector_type(4))) float f32x4;

__device__ __forceinline__ unsigned short f2bf(float f) {
    return __builtin_bit_cast(unsigned short, __float2bfloat16(f));
}

// stage a 128x128 fp32 matrix into padded bf16 LDS, fully coalesced reads
__device__ __forceinline__ void stage_w(const float* __restrict__ w,
                                        unsigned short (*sW)[LDSS], int t) {
    #pragma unroll
    for (int i = 0; i < 16; ++i) {
        const int idx4 = i * 256 + t;            // float4 index, coalesced
        const float4 v = ((const float4*)w)[idx4];
        const int row = idx4 >> 5;               // 32 float4 per row
        const int c4  = (idx4 & 31) * 4;
        ushort4 b;
        b.x = f2bf(v.x); b.y = f2bf(v.y); b.z = f2bf(v.z); b.w = f2bf(v.w);
        *(ushort4*)&sW[row][c4] = b;             // 8B write, 2-way bank alias (free)
    }
}

__global__ __launch_bounds__(256, 2)
void ctx_encoder(const int* __restrict__ nodes,
                 const float* __restrict__ c2e,
                 const float* __restrict__ w1,
                 const float* __restrict__ b1,
                 const float* __restrict__ w2,
                 const float* __restrict__ b2,
                 float* __restrict__ out,
                 int N) {
    __shared__ unsigned short sW[D_DIM][LDSS];   // weights, reused W1 -> W2 (34.8 KB)
    __shared__ unsigned short sH[MT][LDSS];      // h transpose buffer (34.8 KB)

    const int t    = threadIdx.x;
    const int lane = t & 63;
    const int wave = t >> 6;
    const int cl   = lane & 15;
    const int quad = lane >> 4;
    const int base = blockIdx.x * MT + wave * 32;   // wave owns rows [base, base+32)

    // ---- gather 2 rows/lane of A-fragments straight from global (deep MLP) ----
    float4 g[2][8];
    #pragma unroll
    for (int m = 0; m < 2; ++m) {
        int gr = base + m * 16 + cl;
        gr = gr < N ? gr : N - 1;
        const int idx = nodes[gr];
        const float* rowp = c2e + (size_t)idx * D_DIM + quad * 8;
        #pragma unroll
        for (int ks = 0; ks < 4; ++ks) {
            g[m][2 * ks]     = *(const float4*)(rowp + ks * 32);
            g[m][2 * ks + 1] = *(const float4*)(rowp + ks * 32 + 4);
        }
    }

    // ---- stage W1 -> LDS (overlaps with gather latency) ----
    stage_w(w1, sW, t);

    // hoist biases (overlap latency)
    float bias1[8], bias2[8];
    #pragma unroll
    for (int ct = 0; ct < 8; ++ct) {
        bias1[ct] = b1[ct * 16 + cl];
        bias2[ct] = b2[ct * 16 + cl];
    }

    // convert gathered rows to bf16 A-fragments
    bf16x8 aF[2][4];
    #pragma unroll
    for (int m = 0; m < 2; ++m) {
        #pragma unroll
        for (int ks = 0; ks < 4; ++ks) {
            bf16x8 a;
            a[0] = (short)f2bf(g[m][2 * ks].x);     a[1] = (short)f2bf(g[m][2 * ks].y);
            a[2] = (short)f2bf(g[m][2 * ks].z);     a[3] = (short)f2bf(g[m][2 * ks].w);
            a[4] = (short)f2bf(g[m][2 * ks + 1].x); a[5] = (short)f2bf(g[m][2 * ks + 1].y);
            a[6] = (short)f2bf(g[m][2 * ks + 1].z); a[7] = (short)f2bf(g[m][2 * ks + 1].w);
            aF[m][ks] = a;
        }
    }
    __syncthreads();

    // ---- layer 1: h = relu(ce @ W1^T + b1) -> sH (bf16) ----
    #pragma unroll
    for (int ct = 0; ct < 8; ++ct) {
        bf16x8 bF[4];
        #pragma unroll
        for (int ks = 0; ks < 4; ++ks)
            bF[ks] = *(const bf16x8*)&sW[ct * 16 + cl][ks * 32 + quad * 8];
        f32x4 acc[2] = {{0.f,0.f,0.f,0.f},{0.f,0.f,0.f,0.f}};
        #pragma unroll
        for (int m = 0; m < 2; ++m)
            #pragma unroll
            for (int ks = 0; ks < 4; ++ks)
                acc[m] = __builtin_amdgcn_mfma_f32_16x16x32_bf16(aF[m][ks], bF[ks], acc[m], 0, 0, 0);
        const int j = ct * 16 + cl;
        #pragma unroll
        for (int m = 0; m < 2; ++m)
            #pragma unroll
            for (int r = 0; r < 4; ++r) {
                float h = acc[m][r] + bias1[ct];
                h = h > 0.f ? h : 0.f;
                sH[wave * 32 + m * 16 + quad * 4 + r][j] = f2bf(h);
            }
    }
    __syncthreads();   // all done reading W1, all h written

    // ---- stage W2 -> LDS (same buffer) ----
    stage_w(w2, sW, t);
    __syncthreads();

    // ---- layer 2: out = relu(h @ W2^T + b2) ----
    bf16x8 hF[2][4];
    #pragma unroll
    for (int m = 0; m < 2; ++m)
        #pragma unroll
        for (int ks = 0; ks < 4; ++ks)
            hF[m][ks] = *(const bf16x8*)&sH[wave * 32 + m * 16 + cl][ks * 32 + quad * 8];

    #pragma unroll
    for (int ct = 0; ct < 8; ++ct) {
        bf16x8 bF[4];
        #pragma unroll
        for (int ks = 0; ks < 4; ++ks)
            bF[ks] = *(const bf16x8*)&sW[ct * 16 + cl][ks * 32 + quad * 8];
        f32x4 acc[2] = {{0.f,0.f,0.f,0.f},{0.f,0.f,0.f,0.f}};
        #pragma unroll
        for (int m = 0; m < 2; ++m)
            #pragma unroll
            for (int ks = 0; ks < 4; ++ks)
                acc[m] = __builtin_amdgcn_mfma_f32_16x16x32_bf16(hF[m][ks], bF[ks], acc[m], 0, 0, 0);
        const int j = ct * 16 + cl;
        #pragma unroll
        for (int m = 0; m < 2; ++m)
            #pragma unroll
            for (int r = 0; r < 4; ++r) {
                float o = acc[m][r] + bias2[ct];
                o = o > 0.f ? o : 0.f;
                const int grow = base + m * 16 + quad * 4 + r;
                if (grow < N)
                    out[(size_t)grow * D_DIM + j] = o;
            }
    }
}

extern "C" void kernel_launch(void* const* d_in, const int* in_sizes, int n_in,
                              void* d_out, int out_size, void* d_ws, size_t ws_size,
                              hipStream_t stream) {
    const int*   nodes = (const int*)d_in[0];
    const float* c2e   = (const float*)d_in[1];
    const float* w1    = (const float*)d_in[2];
    const float* b1    = (const float*)d_in[3];
    const float* w2    = (const float*)d_in[4];
    const float* b2    = (const float*)d_in[5];
    float* out = (float*)d_out;
    const int N = in_sizes[0];

    const int grid = (N + MT - 1) / MT;
    ctx_encoder<<<dim3(grid), dim3(256), 0, stream>>>(nodes, c2e, w1, b1, w2, b2, out, N);
}